// Round 13
// baseline (122.690 us; speedup 1.0000x reference)
//
#include <hip/hip_runtime.h>
#include <math.h>

#define IMG   256
#define NFULL 177
#define DETN  362
#define NACQ  45
#define PAD   1024

// ws layout (floats): [0,131072) sino ; [131072,262144) sf
#define SINO_OFF 0
#define SF_OFF   131072

#define HALF_T 180.5f                   // (DETN-1)/2
#define SEGL   16                       // S-samples per segment
// Wave-private tile per batch: 640 dwords. Worst 8Tx16S window: span =
// sqrt(7^2+15^2) = 16.55 -> P=28 universally feasible (h<=21.6<=22=640/28).
// Per block: 4 waves x 2 batches x 640 x 4B = 20480 B -> 8 blocks/CU
// x 4 waves = 32 waves/CU (LDS-exact).
#define TILE_W 640

// strip s covers T in [8s, 8s+8); central strips (T~181) dispatch first
__constant__ const int kStripOrd[46] =
    {22,23,21,24,20,25,19,26,18,27,17,28,16,29,15,30,14,31,13,32,
     12,33,11,34,10,35,9,36,8,37,7,38,6,39,5,40,4,41,3,42,2,43,1,44,0,45};

// ---------------------------------------------------------------------------
// Direct HBM->LDS 16B staging (dest = wave-uniform base + lane*16).
__device__ __forceinline__ void gload16(const float* g, float* l) {
    __builtin_amdgcn_global_load_lds(
        (const __attribute__((address_space(1))) void*)g,
        (__attribute__((address_space(3))) void*)l, 16, 0, 0);
}

// ---------------------------------------------------------------------------
// One 8-T strip S-chunk for BOTH batches, barrier-free (R12 inner loop).
// Per segment: lgkm-wait (WAR on prior ds_reads), stage both windows
// (async gload16 interior / masked float4 boundary), wave-level drain
// (vmcnt+lgkm), sample both tiles.
template<int P>
__device__ __forceinline__ float2 radon_strip2(
    const float* __restrict__ img0,
    const float* __restrict__ img1,
    float* tb,                          // wave-private 2*TILE_W floats
    const float c, const float s,
    const float xbase, const float ybase,
    const float xAB_mn, const float yAB_mn, const float yAB_mx,
    const int Slo, const int Shi, const int lane)
{
    constexpr int W4   = P / 4;
    constexpr int HMAX = TILE_W / P;
    const int ts = lane & 7;
    float val0 = 0.0f, val1 = 0.0f;

    for (int Sseg = Slo; Sseg < Shi; Sseg += SEGL) {
        // window (s >= 0 for theta in [0,180))
        const float sv0 = (float)Sseg - HALF_T;
        const float sv1 = sv0 + (float)(SEGL - 1);
        const float xmn = xAB_mn - sv1 * s;
        const float ya  = sv0 * c, yb = sv1 * c;
        const float ymn = yAB_mn + fminf(ya, yb);
        const float ymx = yAB_mx + fmaxf(ya, yb);
        const int ix0  = (int)floorf(xmn) - 1;
        const int iy0  = (int)floorf(ymn) - 1;
        const int ix0a = ix0 & ~3;
        const int h    = min((int)floorf(ymx) + 3 - iy0, HMAX);
        const int total4 = W4 * h;
        const int nfull  = total4 & ~63;
        const bool interior = (ix0a >= 0) & (iy0 >= 0) &
                              (ix0a + P <= IMG) & (iy0 + h <= IMG);

        // prior segment's ds_reads must complete before we overwrite tb
        asm volatile("s_waitcnt lgkmcnt(0)" ::: "memory");

        if (interior) {
            // clamp-free, predicate-free async HBM->LDS stream, shared addr
            const int base0 = iy0 * IMG + ix0a;
            for (int f0 = 0; f0 < nfull; f0 += 64) {
                const int f  = f0 + lane;
                const int r  = f / W4;             // compile-time magic
                const int c4 = f - r * W4;
                const int go = base0 + r * IMG + (c4 << 2);
                gload16(img0 + go, tb + (f0 << 2));
                gload16(img1 + go, tb + TILE_W + (f0 << 2));
            }
            const int f = nfull + lane;            // exec-masked ragged tail
            if (f < total4) {
                const int r  = f / W4;
                const int c4 = f - r * W4;
                const int go = base0 + r * IMG + (c4 << 2);
                gload16(img0 + go, tb + (nfull << 2));
                gload16(img1 + go, tb + TILE_W + (nfull << 2));
            }
        } else {
            // boundary: masked float4 (gx 4-aligned, IMG%4==0 -> all-or-nothing)
            for (int f = lane; f < total4; f += 64) {
                const int r  = f / W4;
                const int c4 = f - r * W4;
                const int gy = iy0 + r;
                const int gx = ix0a + (c4 << 2);
                const bool ok = ((unsigned)gy < (unsigned)IMG) &
                                ((unsigned)gx <= (unsigned)(IMG - 4));
                float4 v0 = make_float4(0.f, 0.f, 0.f, 0.f);
                float4 v1 = v0;
                if (ok) {
                    const int go = gy * IMG + gx;
                    v0 = *(const float4*)(img0 + go);
                    v1 = *(const float4*)(img1 + go);
                }
                *(float4*)(tb + (f << 2)) = v0;
                *(float4*)(tb + TILE_W + (f << 2)) = v1;
            }
        }
        // wave-level drain: async LDS-writes + ds_writes landed
        asm volatile("s_waitcnt vmcnt(0) lgkmcnt(0)" ::: "memory");
        __builtin_amdgcn_sched_barrier(0);

        const float xoff = xbase - (float)ix0a;
        const float yoff = ybase - (float)iy0;
        const int Send = min(Sseg + SEGL, Shi);

        auto samp = [&](float sval) {
            const float xs  = fmaf(-sval, s, xoff);
            const float ys  = fmaf(sval, c, yoff);
            const float x0f = floorf(xs);
            const float y0f = floorf(ys);
            const float wx  = xs - x0f;
            const float wy  = ys - y0f;
            // base fits exactly in float (< 2^24); chain shared by batches
            const int base = (int)fmaf(y0f, (float)P, x0f);
            const float a00 = tb[base];
            const float a01 = tb[base + 1];              // ds_read2 (0,1)
            const float a10 = tb[base + P];
            const float a11 = tb[base + P + 1];          // ds_read2 (P,P+1)
            const float b00 = tb[TILE_W + base];
            const float b01 = tb[TILE_W + base + 1];
            const float b10 = tb[TILE_W + base + P];
            const float b11 = tb[TILE_W + base + P + 1];
            const float ah0 = fmaf(wx, a01 - a00, a00);
            const float ah1 = fmaf(wx, a11 - a10, a10);
            val0 += fmaf(wy, ah1 - ah0, ah0);
            const float bh0 = fmaf(wx, b01 - b00, b00);
            const float bh1 = fmaf(wx, b11 - b10, b10);
            val1 += fmaf(wy, bh1 - bh0, bh0);
        };

        if (Send - Sseg == SEGL) {
            const float s0 = (float)(Sseg + ts) - HALF_T;
            #pragma unroll
            for (int u = 0; u < SEGL / 8; ++u) samp(s0 + (float)(8 * u));
        } else {
            for (int S = Sseg + ts; S < Send; S += 8) samp((float)S - HALF_T);
        }
    }
    return make_float2(val0, val1);
}

// ---------------------------------------------------------------------------
// Kernel A: radon, S-split load balancing. Block = (angle, strip); its 4
// waves take contiguous SEGL-aligned S-QUARTERS of the strip's wave-union
// range -> intra-block balance is +-1 segment by construction. Grid = 177 x
// 46 = 8142 blocks ~ 4 rounds through the 2048 resident slots -> inter-block
// variance averages out. One LDS partial handoff + one __syncthreads per
// block (waves write only their own tile region before the barrier).
__global__ __launch_bounds__(256, 8) void radon_kernel(
    const float* __restrict__ x,
    const float* __restrict__ thetas,
    float* __restrict__ sino)
{
    const int a = blockIdx.x;          // angle
    const int w    = threadIdx.x >> 6; // wave = S-quarter index
    const int lane = threadIdx.x & 63;
    const int sp   = kStripOrd[blockIdx.y];           // strip 0..45
    const int T0   = sp << 3;
    const int tt   = lane >> 3;
    const int ts   = lane & 7;
    const int T    = T0 + tt;

    __shared__ __align__(16) float tile[4][2 * TILE_W];
    float* tb = tile[w];

    const float th = thetas[a] * (float)(M_PI / 180.0);
    const float c = cosf(th);
    const float s = sinf(th);
    const float cx = (IMG - 1) * 0.5f;
    const float cy = (IMG - 1) * 0.5f;
    const float Tc = (float)T - HALF_T;
    const float xbase = Tc * c + cx;   // xs = xbase - sval*s
    const float ybase = Tc * s + cy;   // ys = ybase + sval*c

    // per-thread valid-S clipping -> wave union (8 T's; same for all waves)
    float lo = -1e30f, hi = 1e30f;
    bool empty = (T >= DETN);
    {   const float aa = -s;
        if (aa > 1e-5f)       { lo = fmaxf(lo, (-1.0f - xbase) / aa); hi = fminf(hi, (256.0f - xbase) / aa); }
        else if (aa < -1e-5f) { lo = fmaxf(lo, (256.0f - xbase) / aa); hi = fminf(hi, (-1.0f - xbase) / aa); }
        else if (xbase <= -1.0f || xbase >= 256.0f) empty = true;
    }
    {   const float aa = c;
        if (aa > 1e-5f)       { lo = fmaxf(lo, (-1.0f - ybase) / aa); hi = fminf(hi, (256.0f - ybase) / aa); }
        else if (aa < -1e-5f) { lo = fmaxf(lo, (256.0f - ybase) / aa); hi = fminf(hi, (-1.0f - ybase) / aa); }
        else if (ybase <= -1.0f || ybase >= 256.0f) empty = true;
    }
    lo = fmaxf(lo, -200.0f);
    hi = fminf(hi, 200.0f);
    int Slo = max(0, (int)floorf(lo + HALF_T) - 1);
    int Shi = min(DETN, (int)floorf(hi + HALF_T) + 2);
    if (empty || Shi < Slo) { Slo = 0; Shi = 0; }

    int wlo = (Shi > Slo) ? Slo : DETN;
    int whi = (Shi > Slo) ? Shi : 0;
    #pragma unroll
    for (int d = 1; d < 64; d <<= 1) {
        wlo = min(wlo, __shfl_xor(wlo, d, 64));
        whi = max(whi, __shfl_xor(whi, d, 64));
    }

    // SEGL-aligned S-quarter for this wave
    const int range = max(whi - wlo, 0);
    const int nseg  = (range + SEGL - 1) / SEGL;
    const int per   = (nseg + 3) >> 2;               // segments per wave
    const int q_lo  = wlo + w * per * SEGL;
    const int q_hi  = min(q_lo + per * SEGL, whi);

    // per-wave pitch selection (registers only; all lanes converge).
    // Bank model: lane (tt,ts) reads at addr ~ tt*dT + ts*dS, dT=s*P+c,
    // dS=c*P-s; multiplicity via 5-bit ballot match + popcount, wave-max.
    // Feasibility: spanx = 7|c|+15|s| <= P-8.05, spany = 7|s|+15|c| <=
    // Hmax-5.05. P=28 universally feasible (max span 16.55 <= 19.95/16.95).
    int best = 2;                       // P=28 safety anchor
    {
        const float ac = fabsf(c), as = fabsf(s);
        const float spanx = 7.f * ac + 15.f * as;
        const float spany = 7.f * as + 15.f * ac;
        const float Pc[4] = {20.f, 24.f, 28.f, 32.f};
        const int   Hm[4] = {32, 26, 22, 20};           // TILE_W / P
        int bcost = 1 << 30;
        #pragma unroll
        for (int p = 0; p < 4; ++p) {
            const float Pf = Pc[p];
            const float dT = s * Pf + c;
            const float dS = c * Pf - s;
            const int bank = (int)floorf((float)tt * dT + (float)ts * dS + 0.5f) & 31;
            unsigned long long m = ~0ull;
            #pragma unroll
            for (int bit = 0; bit < 5; ++bit) {
                const unsigned long long bb = __ballot((bank >> bit) & 1);
                m &= ((bank >> bit) & 1) ? bb : ~bb;
            }
            int cnt = __popcll(m);
            #pragma unroll
            for (int d = 1; d < 64; d <<= 1) cnt = max(cnt, __shfl_xor(cnt, d, 64));
            const bool fit = (spanx <= Pf - 8.05f) && (spany <= (float)Hm[p] - 5.05f);
            if (fit && cnt < bcost) { bcost = cnt; best = p; }
        }
    }

    // hoisted strip-corner terms (T extremes of this 8-T strip)
    const float TcA = (float)T0 - HALF_T;
    const float TcB = (float)(T0 + 7) - HALF_T;
    const float xAB_mn = fminf(TcA * c + cx, TcB * c + cx);
    const float yAB_mn = fminf(TcA * s + cy, TcB * s + cy);
    const float yAB_mx = fmaxf(TcA * s + cy, TcB * s + cy);

    const float* __restrict__ img0 = x;
    const float* __restrict__ img1 = x + IMG * IMG;

    float2 val;
    switch (best) {
    case 0:  val = radon_strip2<20>(img0, img1, tb, c, s, xbase, ybase,
                                    xAB_mn, yAB_mn, yAB_mx, q_lo, q_hi, lane); break;
    case 1:  val = radon_strip2<24>(img0, img1, tb, c, s, xbase, ybase,
                                    xAB_mn, yAB_mn, yAB_mx, q_lo, q_hi, lane); break;
    case 2:  val = radon_strip2<28>(img0, img1, tb, c, s, xbase, ybase,
                                    xAB_mn, yAB_mn, yAB_mx, q_lo, q_hi, lane); break;
    default: val = radon_strip2<32>(img0, img1, tb, c, s, xbase, ybase,
                                    xAB_mn, yAB_mn, yAB_mx, q_lo, q_hi, lane); break;
    }

    // ts-phase reduce within the wave (8-lane groups)
    val.x += __shfl_xor(val.x, 1, 8);
    val.x += __shfl_xor(val.x, 2, 8);
    val.x += __shfl_xor(val.x, 4, 8);
    val.y += __shfl_xor(val.y, 1, 8);
    val.y += __shfl_xor(val.y, 2, 8);
    val.y += __shfl_xor(val.y, 4, 8);

    // cross-wave reduce via each wave's OWN tile region (no hazard before
    // the barrier; sampling of this wave is complete, ds ops are in-order)
    if (ts == 0) {                     // lanes 0,8,..,56: tt = lane>>3
        tb[2 * tt]     = val.x;
        tb[2 * tt + 1] = val.y;
    }
    __syncthreads();
    if (w == 0 && lane < 16) {         // tt2 = lane>>1, batch = lane&1
        const float sum = tile[0][lane] + tile[1][lane]
                        + tile[2][lane] + tile[3][lane];
        const int T2 = T0 + (lane >> 1);
        const int bb = lane & 1;
        if (T2 < DETN) {
            sino[(bb * NFULL + a) * DETN + T2] = sum;
        }
    }
}

// ---------------------------------------------------------------------------
// Kernel B: data-consistency + ramp filter (unchanged).
__global__ __launch_bounds__(192) void dc_filter_kernel(
    const float* __restrict__ sino,
    const float* __restrict__ st,
    const int*   __restrict__ acq,
    float* __restrict__ sf)
{
    const int blk = blockIdx.x;
    const int b = blk / NFULL;
    const int a = blk - b * NFULL;
    const int tid = threadIdx.x;

    __shared__ float col[DETN];
    __shared__ float gf[PAD];

    const float SC = (float)(M_PI / (2.0 * NFULL));
    const float c0 = 0.5f * SC;
    for (int n = tid; n < PAD; n += 192) {
        float v = 0.0f;
        if (n & 1) {
            const int d = (n < PAD - n) ? n : (PAD - n);
            const float pd = (float)M_PI * (float)d;
            v = -2.0f / (pd * pd) * SC;
        }
        gf[n] = v;
    }

    int inv = -1;
    for (int i = 0; i < NACQ; ++i) {
        if (acq[i] == a) inv = i;
    }

    for (int m = tid; m < DETN; m += 192) {
        float val = sino[(b * NFULL + a) * DETN + m];
        if (inv >= 0) {
            val = st[(b * DETN + m) * NACQ + inv] - val;
        }
        col[m] = val;
    }
    __syncthreads();

    const int T = blockIdx.y * 181 + tid;
    if (tid < 181) {
        const int m0 = (T + 1) & 1;
        float acc = c0 * col[T];
        #pragma unroll 4
        for (int k = 0; k < 181; ++k) {
            const int m = m0 + 2 * k;
            acc += col[m] * gf[(T - m) & (PAD - 1)];
        }
        sf[(b * NFULL + a) * DETN + T] = acc;
    }
}

// ---------------------------------------------------------------------------
// Kernel C: backprojection (unchanged).
__global__ __launch_bounds__(256) void backproject_kernel(
    const float* __restrict__ sf,
    const float* __restrict__ thetas,
    float* __restrict__ out)
{
    __shared__ float cb[2 * NFULL];
    __shared__ float red[256];
    const int tid = threadIdx.x;
    const int lane  = tid & 63;
    const int phase = tid >> 6;
    const int pix = blockIdx.x * 64 + lane;
    const int b = pix >> 16;
    const int y = (pix >> 8) & 255;
    const int xq = pix & 255;
    const float gx = (float)xq - (IMG - 1) * 0.5f;
    const float gy = (float)y  - (IMG - 1) * 0.5f;

    for (int a = tid; a < NFULL; a += 256) {
        float th = thetas[a] * (float)(M_PI / 180.0);
        cb[2 * a]     = cosf(th);
        cb[2 * a + 1] = fmaf(sinf(th), gy, HALF_T);
    }
    __syncthreads();

    const float* __restrict__ sfb = sf + b * NFULL * DETN;

    float acc = 0.0f;
    #pragma unroll 4
    for (int a = phase; a < NFULL; a += 4) {
        const float cs = cb[2 * a];
        const float bs = cb[2 * a + 1];
        const float t = fmaf(cs, gx, bs);
        const float t0f = floorf(t);
        const float w = t - t0f;
        const float* row = sfb + a * DETN + (int)t0f;
        const float v0 = row[0];
        const float v1 = row[1];
        acc += v0 + w * (v1 - v0);
    }
    red[tid] = acc;
    __syncthreads();
    if (tid < 64) {
        out[blockIdx.x * 64 + tid] =
            red[tid] + red[tid + 64] + red[tid + 128] + red[tid + 192];
    }
}

extern "C" void kernel_launch(void* const* d_in, const int* in_sizes, int n_in,
                              void* d_out, int out_size, void* d_ws, size_t ws_size,
                              hipStream_t stream) {
    const float* x      = (const float*)d_in[0];
    const float* st     = (const float*)d_in[1];
    const float* thetas = (const float*)d_in[2];
    const int*   acq    = (const int*)d_in[3];
    float* out  = (float*)d_out;
    float* wsf  = (float*)d_ws;
    float* sino = wsf + SINO_OFF;
    float* sf   = wsf + SF_OFF;

    dim3 gA(NFULL, 46);                               // (angle, strip) blocks
    radon_kernel<<<gA, 256, 0, stream>>>(x, thetas, sino);
    dim3 gB(2 * NFULL, 2);
    dc_filter_kernel<<<gB, 192, 0, stream>>>(sino, st, acq, sf);
    backproject_kernel<<<(2 * IMG * IMG) / 64, 256, 0, stream>>>(sf, thetas, out);
}

// Round 14
// 111.572 us; speedup vs baseline: 1.0997x; 1.0997x over previous
//
#include <hip/hip_runtime.h>
#include <math.h>

#define IMG   256
#define NFULL 177
#define DETN  362
#define NACQ  45
#define PAD   1024

// ws layout (floats): [0,131072) sino ; [131072,262144) sf
#define SINO_OFF 0
#define SF_OFF   131072

#define HALF_T 180.5f                   // (DETN-1)/2
#define SEGL   16                       // S-samples per segment
// Wave-private tile per batch: 640 dwords. Worst 8Tx16S window: span =
// sqrt(7^2+15^2) = 16.55 -> P=28 universally feasible (h<=21.6<=22=640/28).
// Per block: 4 waves x 2 batches x 640 x 4B = 20480 B -> 8 blocks/CU
// x 4 waves = 32 waves/CU (LDS-exact).
#define TILE_W 640

// strip s covers T in [8s, 8s+8); central strips (T~181) dispatch first.
// Blocks pair ADJACENT entries (similar work) -> intra-block balance.
__constant__ const int kStripOrd[46] =
    {22,23,21,24,20,25,19,26,18,27,17,28,16,29,15,30,14,31,13,32,
     12,33,11,34,10,35,9,36,8,37,7,38,6,39,5,40,4,41,3,42,2,43,1,44,0,45};

// ---------------------------------------------------------------------------
// Direct HBM->LDS 16B staging (dest = wave-uniform base + lane*16).
__device__ __forceinline__ void gload16(const float* g, float* l) {
    __builtin_amdgcn_global_load_lds(
        (const __attribute__((address_space(1))) void*)g,
        (__attribute__((address_space(3))) void*)l, 16, 0, 0);
}

// ---------------------------------------------------------------------------
// One 8-T strip S-chunk for BOTH batches, barrier-free (R12 inner loop).
// Per segment: lgkm-wait (WAR on prior ds_reads), stage both windows
// (async gload16 interior / masked float4 boundary), wave-level drain
// (vmcnt+lgkm), sample both tiles.
template<int P>
__device__ __forceinline__ float2 radon_strip2(
    const float* __restrict__ img0,
    const float* __restrict__ img1,
    float* tb,                          // wave-private 2*TILE_W floats
    const float c, const float s,
    const float xbase, const float ybase,
    const float xAB_mn, const float yAB_mn, const float yAB_mx,
    const int Slo, const int Shi, const int lane)
{
    constexpr int W4   = P / 4;
    constexpr int HMAX = TILE_W / P;
    const int ts = lane & 7;
    float val0 = 0.0f, val1 = 0.0f;

    for (int Sseg = Slo; Sseg < Shi; Sseg += SEGL) {
        // window (s >= 0 for theta in [0,180))
        const float sv0 = (float)Sseg - HALF_T;
        const float sv1 = sv0 + (float)(SEGL - 1);
        const float xmn = xAB_mn - sv1 * s;
        const float ya  = sv0 * c, yb = sv1 * c;
        const float ymn = yAB_mn + fminf(ya, yb);
        const float ymx = yAB_mx + fmaxf(ya, yb);
        const int ix0  = (int)floorf(xmn) - 1;
        const int iy0  = (int)floorf(ymn) - 1;
        const int ix0a = ix0 & ~3;
        const int h    = min((int)floorf(ymx) + 3 - iy0, HMAX);
        const int total4 = W4 * h;
        const int nfull  = total4 & ~63;
        const bool interior = (ix0a >= 0) & (iy0 >= 0) &
                              (ix0a + P <= IMG) & (iy0 + h <= IMG);

        // prior segment's ds_reads must complete before we overwrite tb
        asm volatile("s_waitcnt lgkmcnt(0)" ::: "memory");

        if (interior) {
            // clamp-free, predicate-free async HBM->LDS stream, shared addr
            const int base0 = iy0 * IMG + ix0a;
            for (int f0 = 0; f0 < nfull; f0 += 64) {
                const int f  = f0 + lane;
                const int r  = f / W4;             // compile-time magic
                const int c4 = f - r * W4;
                const int go = base0 + r * IMG + (c4 << 2);
                gload16(img0 + go, tb + (f0 << 2));
                gload16(img1 + go, tb + TILE_W + (f0 << 2));
            }
            const int f = nfull + lane;            // exec-masked ragged tail
            if (f < total4) {
                const int r  = f / W4;
                const int c4 = f - r * W4;
                const int go = base0 + r * IMG + (c4 << 2);
                gload16(img0 + go, tb + (nfull << 2));
                gload16(img1 + go, tb + TILE_W + (nfull << 2));
            }
        } else {
            // boundary: masked float4 (gx 4-aligned, IMG%4==0 -> all-or-nothing)
            for (int f = lane; f < total4; f += 64) {
                const int r  = f / W4;
                const int c4 = f - r * W4;
                const int gy = iy0 + r;
                const int gx = ix0a + (c4 << 2);
                const bool ok = ((unsigned)gy < (unsigned)IMG) &
                                ((unsigned)gx <= (unsigned)(IMG - 4));
                float4 v0 = make_float4(0.f, 0.f, 0.f, 0.f);
                float4 v1 = v0;
                if (ok) {
                    const int go = gy * IMG + gx;
                    v0 = *(const float4*)(img0 + go);
                    v1 = *(const float4*)(img1 + go);
                }
                *(float4*)(tb + (f << 2)) = v0;
                *(float4*)(tb + TILE_W + (f << 2)) = v1;
            }
        }
        // wave-level drain: async LDS-writes + ds_writes landed
        asm volatile("s_waitcnt vmcnt(0) lgkmcnt(0)" ::: "memory");
        __builtin_amdgcn_sched_barrier(0);

        const float xoff = xbase - (float)ix0a;
        const float yoff = ybase - (float)iy0;
        const int Send = min(Sseg + SEGL, Shi);

        auto samp = [&](float sval) {
            const float xs  = fmaf(-sval, s, xoff);
            const float ys  = fmaf(sval, c, yoff);
            const float x0f = floorf(xs);
            const float y0f = floorf(ys);
            const float wx  = xs - x0f;
            const float wy  = ys - y0f;
            // base fits exactly in float (< 2^24); chain shared by batches
            const int base = (int)fmaf(y0f, (float)P, x0f);
            const float a00 = tb[base];
            const float a01 = tb[base + 1];              // ds_read2 (0,1)
            const float a10 = tb[base + P];
            const float a11 = tb[base + P + 1];          // ds_read2 (P,P+1)
            const float b00 = tb[TILE_W + base];
            const float b01 = tb[TILE_W + base + 1];
            const float b10 = tb[TILE_W + base + P];
            const float b11 = tb[TILE_W + base + P + 1];
            const float ah0 = fmaf(wx, a01 - a00, a00);
            const float ah1 = fmaf(wx, a11 - a10, a10);
            val0 += fmaf(wy, ah1 - ah0, ah0);
            const float bh0 = fmaf(wx, b01 - b00, b00);
            const float bh1 = fmaf(wx, b11 - b10, b10);
            val1 += fmaf(wy, bh1 - bh0, bh0);
        };

        if (Send - Sseg == SEGL) {
            const float s0 = (float)(Sseg + ts) - HALF_T;
            #pragma unroll
            for (int u = 0; u < SEGL / 8; ++u) samp(s0 + (float)(8 * u));
        } else {
            for (int S = Sseg + ts; S < Send; S += 8) samp((float)S - HALF_T);
        }
    }
    return make_float2(val0, val1);
}

// ---------------------------------------------------------------------------
// Kernel A: radon, half-strip balancing. Block = 2 adjacent-length strips x
// 2 SEGL-aligned S-HALVES (4 waves). Grid = 177 x 23 = 4071 blocks ~ 2
// scheduling rounds, long blocks first -> backfill averages the tail.
// Max block work = half a central strip (~12 segments). Strip reduce is
// intra-block: one LDS handoff + one __syncthreads. Pitch P from {24,28}
// (slimmed ballot scorer; P=28 universally feasible).
__global__ __launch_bounds__(256, 8) void radon_kernel(
    const float* __restrict__ x,
    const float* __restrict__ thetas,
    float* __restrict__ sino)
{
    const int a = blockIdx.x;          // angle
    const int w    = threadIdx.x >> 6; // wave: strip = w>>1, S-half = w&1
    const int lane = threadIdx.x & 63;
    const int sidx = (blockIdx.y << 1) | (w >> 1);    // 0..45
    const int sp   = kStripOrd[sidx];                 // strip 0..45
    const int T0   = sp << 3;
    const int tt   = lane >> 3;
    const int ts   = lane & 7;
    const int T    = T0 + tt;

    __shared__ __align__(16) float tile[4][2 * TILE_W];
    float* tb = tile[w];

    const float th = thetas[a] * (float)(M_PI / 180.0);
    const float c = cosf(th);
    const float s = sinf(th);
    const float cx = (IMG - 1) * 0.5f;
    const float cy = (IMG - 1) * 0.5f;
    const float Tc = (float)T - HALF_T;
    const float xbase = Tc * c + cx;   // xs = xbase - sval*s
    const float ybase = Tc * s + cy;   // ys = ybase + sval*c

    // per-thread valid-S clipping -> wave union (8 T's of this strip)
    float lo = -1e30f, hi = 1e30f;
    bool empty = (T >= DETN);
    {   const float aa = -s;
        if (aa > 1e-5f)       { lo = fmaxf(lo, (-1.0f - xbase) / aa); hi = fminf(hi, (256.0f - xbase) / aa); }
        else if (aa < -1e-5f) { lo = fmaxf(lo, (256.0f - xbase) / aa); hi = fminf(hi, (-1.0f - xbase) / aa); }
        else if (xbase <= -1.0f || xbase >= 256.0f) empty = true;
    }
    {   const float aa = c;
        if (aa > 1e-5f)       { lo = fmaxf(lo, (-1.0f - ybase) / aa); hi = fminf(hi, (256.0f - ybase) / aa); }
        else if (aa < -1e-5f) { lo = fmaxf(lo, (256.0f - ybase) / aa); hi = fminf(hi, (-1.0f - ybase) / aa); }
        else if (ybase <= -1.0f || ybase >= 256.0f) empty = true;
    }
    lo = fmaxf(lo, -200.0f);
    hi = fminf(hi, 200.0f);
    int Slo = max(0, (int)floorf(lo + HALF_T) - 1);
    int Shi = min(DETN, (int)floorf(hi + HALF_T) + 2);
    if (empty || Shi < Slo) { Slo = 0; Shi = 0; }

    int wlo = (Shi > Slo) ? Slo : DETN;
    int whi = (Shi > Slo) ? Shi : 0;
    #pragma unroll
    for (int d = 1; d < 64; d <<= 1) {
        wlo = min(wlo, __shfl_xor(wlo, d, 64));
        whi = max(whi, __shfl_xor(whi, d, 64));
    }

    // SEGL-aligned S-half for this wave
    const int range = max(whi - wlo, 0);
    const int nseg  = (range + SEGL - 1) / SEGL;
    const int per   = (nseg + 1) >> 1;               // segments per half
    const int q_lo  = wlo + (w & 1) * per * SEGL;
    const int q_hi  = min(q_lo + per * SEGL, whi);

    // slim pitch selection: P in {24,28} by ballot bank-multiplicity.
    // Bank model: lane (tt,ts) reads at addr ~ tt*dT + ts*dS, dT=s*P+c,
    // dS=c*P-s. Feasibility: spanx=7|c|+15|s| <= P-8.05, spany=7|s|+15|c|
    // <= Hmax-5.05. P=28 universally feasible (16.55 <= 19.95/16.95).
    int best = 1;                       // P=28 safety anchor
    {
        const float ac = fabsf(c), as = fabsf(s);
        const float spanx = 7.f * ac + 15.f * as;
        const float spany = 7.f * as + 15.f * ac;
        const float Pc[2] = {24.f, 28.f};
        const int   Hm[2] = {26, 22};                   // TILE_W / P
        int bcost = 1 << 30;
        #pragma unroll
        for (int p = 0; p < 2; ++p) {
            const float Pf = Pc[p];
            const float dT = s * Pf + c;
            const float dS = c * Pf - s;
            const int bank = (int)floorf((float)tt * dT + (float)ts * dS + 0.5f) & 31;
            unsigned long long m = ~0ull;
            #pragma unroll
            for (int bit = 0; bit < 5; ++bit) {
                const unsigned long long bb = __ballot((bank >> bit) & 1);
                m &= ((bank >> bit) & 1) ? bb : ~bb;
            }
            int cnt = __popcll(m);
            #pragma unroll
            for (int d = 1; d < 64; d <<= 1) cnt = max(cnt, __shfl_xor(cnt, d, 64));
            const bool fit = (spanx <= Pf - 8.05f) && (spany <= (float)Hm[p] - 5.05f);
            if (fit && cnt < bcost) { bcost = cnt; best = p; }
        }
    }

    // hoisted strip-corner terms (T extremes of this 8-T strip)
    const float TcA = (float)T0 - HALF_T;
    const float TcB = (float)(T0 + 7) - HALF_T;
    const float xAB_mn = fminf(TcA * c + cx, TcB * c + cx);
    const float yAB_mn = fminf(TcA * s + cy, TcB * s + cy);
    const float yAB_mx = fmaxf(TcA * s + cy, TcB * s + cy);

    const float* __restrict__ img0 = x;
    const float* __restrict__ img1 = x + IMG * IMG;

    float2 val;
    if (best == 0) {
        val = radon_strip2<24>(img0, img1, tb, c, s, xbase, ybase,
                               xAB_mn, yAB_mn, yAB_mx, q_lo, q_hi, lane);
    } else {
        val = radon_strip2<28>(img0, img1, tb, c, s, xbase, ybase,
                               xAB_mn, yAB_mn, yAB_mx, q_lo, q_hi, lane);
    }

    // ts-phase reduce within the wave (8-lane groups)
    val.x += __shfl_xor(val.x, 1, 8);
    val.x += __shfl_xor(val.x, 2, 8);
    val.x += __shfl_xor(val.x, 4, 8);
    val.y += __shfl_xor(val.y, 1, 8);
    val.y += __shfl_xor(val.y, 2, 8);
    val.y += __shfl_xor(val.y, 4, 8);

    // cross-wave reduce via each wave's OWN tile region (no hazard before
    // the barrier; this wave's sampling is done, ds ops are in-order)
    if (ts == 0) {                     // lanes 0,8,..,56: tt = lane>>3
        tb[2 * tt]     = val.x;
        tb[2 * tt + 1] = val.y;
    }
    __syncthreads();
    if (w == 0 && lane < 32) {         // pair = lane>>4, k = lane&15
        const int pair = lane >> 4;    // 0: strips waves 0+1, 1: waves 2+3
        const int k    = lane & 15;    // 2*tt + batch
        const float sum = tile[2 * pair][k] + tile[2 * pair + 1][k];
        const int spo = kStripOrd[(blockIdx.y << 1) | pair];
        const int T2  = (spo << 3) + (k >> 1);
        const int bb  = k & 1;
        if (T2 < DETN) {
            sino[(bb * NFULL + a) * DETN + T2] = sum;
        }
    }
}

// ---------------------------------------------------------------------------
// Kernel B: data-consistency + ramp filter (unchanged).
__global__ __launch_bounds__(192) void dc_filter_kernel(
    const float* __restrict__ sino,
    const float* __restrict__ st,
    const int*   __restrict__ acq,
    float* __restrict__ sf)
{
    const int blk = blockIdx.x;
    const int b = blk / NFULL;
    const int a = blk - b * NFULL;
    const int tid = threadIdx.x;

    __shared__ float col[DETN];
    __shared__ float gf[PAD];

    const float SC = (float)(M_PI / (2.0 * NFULL));
    const float c0 = 0.5f * SC;
    for (int n = tid; n < PAD; n += 192) {
        float v = 0.0f;
        if (n & 1) {
            const int d = (n < PAD - n) ? n : (PAD - n);
            const float pd = (float)M_PI * (float)d;
            v = -2.0f / (pd * pd) * SC;
        }
        gf[n] = v;
    }

    int inv = -1;
    for (int i = 0; i < NACQ; ++i) {
        if (acq[i] == a) inv = i;
    }

    for (int m = tid; m < DETN; m += 192) {
        float val = sino[(b * NFULL + a) * DETN + m];
        if (inv >= 0) {
            val = st[(b * DETN + m) * NACQ + inv] - val;
        }
        col[m] = val;
    }
    __syncthreads();

    const int T = blockIdx.y * 181 + tid;
    if (tid < 181) {
        const int m0 = (T + 1) & 1;
        float acc = c0 * col[T];
        #pragma unroll 4
        for (int k = 0; k < 181; ++k) {
            const int m = m0 + 2 * k;
            acc += col[m] * gf[(T - m) & (PAD - 1)];
        }
        sf[(b * NFULL + a) * DETN + T] = acc;
    }
}

// ---------------------------------------------------------------------------
// Kernel C: backprojection (unchanged).
__global__ __launch_bounds__(256) void backproject_kernel(
    const float* __restrict__ sf,
    const float* __restrict__ thetas,
    float* __restrict__ out)
{
    __shared__ float cb[2 * NFULL];
    __shared__ float red[256];
    const int tid = threadIdx.x;
    const int lane  = tid & 63;
    const int phase = tid >> 6;
    const int pix = blockIdx.x * 64 + lane;
    const int b = pix >> 16;
    const int y = (pix >> 8) & 255;
    const int xq = pix & 255;
    const float gx = (float)xq - (IMG - 1) * 0.5f;
    const float gy = (float)y  - (IMG - 1) * 0.5f;

    for (int a = tid; a < NFULL; a += 256) {
        float th = thetas[a] * (float)(M_PI / 180.0);
        cb[2 * a]     = cosf(th);
        cb[2 * a + 1] = fmaf(sinf(th), gy, HALF_T);
    }
    __syncthreads();

    const float* __restrict__ sfb = sf + b * NFULL * DETN;

    float acc = 0.0f;
    #pragma unroll 4
    for (int a = phase; a < NFULL; a += 4) {
        const float cs = cb[2 * a];
        const float bs = cb[2 * a + 1];
        const float t = fmaf(cs, gx, bs);
        const float t0f = floorf(t);
        const float w = t - t0f;
        const float* row = sfb + a * DETN + (int)t0f;
        const float v0 = row[0];
        const float v1 = row[1];
        acc += v0 + w * (v1 - v0);
    }
    red[tid] = acc;
    __syncthreads();
    if (tid < 64) {
        out[blockIdx.x * 64 + tid] =
            red[tid] + red[tid + 64] + red[tid + 128] + red[tid + 192];
    }
}

extern "C" void kernel_launch(void* const* d_in, const int* in_sizes, int n_in,
                              void* d_out, int out_size, void* d_ws, size_t ws_size,
                              hipStream_t stream) {
    const float* x      = (const float*)d_in[0];
    const float* st     = (const float*)d_in[1];
    const float* thetas = (const float*)d_in[2];
    const int*   acq    = (const int*)d_in[3];
    float* out  = (float*)d_out;
    float* wsf  = (float*)d_ws;
    float* sino = wsf + SINO_OFF;
    float* sf   = wsf + SF_OFF;

    dim3 gA(NFULL, 23);                  // (angle, strip-pair) blocks
    radon_kernel<<<gA, 256, 0, stream>>>(x, thetas, sino);
    dim3 gB(2 * NFULL, 2);
    dc_filter_kernel<<<gB, 192, 0, stream>>>(sino, st, acq, sf);
    backproject_kernel<<<(2 * IMG * IMG) / 64, 256, 0, stream>>>(sf, thetas, out);
}